// Round 7
// baseline (16.062 us; speedup 1.0000x reference)
//
#include <hip/hip_runtime.h>
#include <limits.h>

// BKT: B=4096 students, T=512 timesteps, K=2048 skills.
// R7 = R6 + k0 staged in LDS. R6 (rank-0 fast path, 32 waves/CU) got
// 19.0 -> 15.5 us. Remaining modeled costs: HBM ~3.9us, VALU issue ~3us,
// and the universal scattered k0[sk] gather ~2.9us of L1 line-serialized
// time (8 gather instrs/block x ~55 lines x 16 blocks/CU). This round:
// k0 -> LDS (8 KB, coalesced float4 stage; gather becomes random-bank
// ds_read ~1.5x base cost). nxt_s compressed to short (head stays int:
// LDS atomics are 32-bit). head init via int4. LDS 19 KB -> 8 blocks/CU,
// still 32 waves/CU.

#define BKT_B 4096
#define BKT_T 512
#define BKT_K 2048
#define BLK   256
#define TPT   (BKT_T / BLK)   // 2 timesteps per thread

__global__ __launch_bounds__(BLK) void bkt_kernel(
    const int* __restrict__ skills,
    const float* __restrict__ resp,
    const float* __restrict__ k0,
    const float* __restrict__ tp,
    const float* __restrict__ gp,
    const float* __restrict__ sp,
    float* __restrict__ out) {
  __shared__ int   head_s[BKT_K];   // per-skill list head (int: 32b atomics)
  __shared__ float k0_s[BKT_K];     // staged prior table
  __shared__ short nxt_s[BKT_T];    // linked-list next (arbitrary order)
  __shared__ float resp_s[BKT_T];

  const int b = blockIdx.x;
  const int base = b * BKT_T;
  const int tid = threadIdx.x;

  // issue all global loads first (coalesced); overlap with LDS init below
  int   sk[TPT];
  float rr[TPT];
#pragma unroll
  for (int u = 0; u < TPT; ++u) {
    const int t = tid + u * BLK;
    sk[u] = skills[base + t];
    rr[u] = resp[base + t];
  }
  float4 k0v[2];
  {
    const float4* k04 = (const float4*)k0;
#pragma unroll
    for (int i = 0; i < 2; ++i)      // 2048/4/256 = 2
      k0v[i] = k04[tid + i * BLK];
  }

  // head-table init via 16B LDS stores (2 instrs/thread)
  {
    int4* h4 = (int4*)head_s;
#pragma unroll
    for (int i = 0; i < 2; ++i)
      h4[tid + i * BLK] = make_int4(-1, -1, -1, -1);
  }
  // stage k0 + responses
  {
    float4* k0s4 = (float4*)k0_s;
#pragma unroll
    for (int i = 0; i < 2; ++i)
      k0s4[tid + i * BLK] = k0v[i];
  }
#pragma unroll
  for (int u = 0; u < TPT; ++u)
    resp_s[tid + u * BLK] = rr[u];
  __syncthreads();

  // build per-skill linked lists (order irrelevant)
#pragma unroll
  for (int u = 0; u < TPT; ++u) {
    const int t = tid + u * BLK;
    nxt_s[t] = (short)atomicExch(&head_s[sk[u]], t);
  }
  __syncthreads();

#pragma unroll
  for (int u = 0; u < TPT; ++u) {
    const int t = tid + u * BLK;
    const int s_ = sk[u];

    // one walk: count earlier same-skill touches
    const int head = head_s[s_];
    int rank = 0;
    for (int j = head; j >= 0; j = nxt_s[j])
      rank += (j < t);

    float p = k0_s[s_];              // first-touch prior (rank-0 answer)

    if (rank > 0) {                  // ~12% of lanes: replay prefix in order
      const float ss = sp[s_];
      const float gg = gp[s_];
      const float tt = tp[s_];
      int cur = -1;
      for (int rd = 0; rd < rank; ++rd) {
        int best = INT_MAX;
        for (int j = head; j >= 0; j = nxt_s[j])
          if (j < t && j > cur) best = min(best, j);
        const float r = resp_s[best];
        float num, den;
        if (r > 0.5f) {              // correct response
          num = p * (1.0f - ss);
          den = num + (1.0f - p) * gg;
        } else {                     // incorrect response
          num = p * ss;
          den = num + (1.0f - p) * (1.0f - gg);
        }
        const float q = num / den;   // Bayesian posterior
        p = q + (1.0f - q) * tt;     // learning transition
        cur = best;
      }
    }

    out[base + t] = p;               // emit pre-update mastery
  }
}

extern "C" void kernel_launch(void* const* d_in, const int* in_sizes, int n_in,
                              void* d_out, int out_size, void* d_ws, size_t ws_size,
                              hipStream_t stream) {
  const int*   skills = (const int*)d_in[0];
  const float* resp   = (const float*)d_in[1];
  const float* k0     = (const float*)d_in[2];
  const float* tp     = (const float*)d_in[3];
  const float* gp     = (const float*)d_in[4];
  const float* sp     = (const float*)d_in[5];
  float* out = (float*)d_out;

  bkt_kernel<<<BKT_B, BLK, 0, stream>>>(skills, resp, k0, tp, gp, sp, out);
}